// Round 1
// baseline (241.100 us; speedup 1.0000x reference)
//
#include <hip/hip_runtime.h>
#include <hip/hip_bf16.h>

// Problem constants (fixed by the reference)
#define DIM 128      // IN_DIM == COM_DIM
#define NE  5        // N_ETYPE
#define NH  4        // N_HEADS
#define NHT (NH*NE)  // 20 channels, layout k = h*NE + t
#define CAP 64       // bucket capacity per dst (Poisson(20) max ~50; P(>=64)~2e-9)

typedef unsigned short u16;
typedef unsigned int   u32;
typedef __attribute__((ext_vector_type(8))) short bf8v;  // 8 bf16 = 4 VGPRs (MFMA A/B frag)
typedef __attribute__((ext_vector_type(4))) float f4v;   // MFMA C/D frag

__device__ __forceinline__ float bf2f(u16 u) {
    union { u32 i; float f; } v; v.i = ((u32)u) << 16; return v.f;
}
__device__ __forceinline__ u16 f2bf(float f) {
    union { float f; u32 i; } v; v.f = f;
    u32 x = v.i;
    return (u16)((x + 0x7FFFu + ((x >> 16) & 1u)) >> 16);  // RNE
}
// leaky-relu + clamp to +-60 (overflow armor; softmax ratio needs no max-sub)
__device__ __forceinline__ float edge_act(float e) {
    e = e >= 0.f ? e : 0.2f * e;
    e = fminf(e, 60.f);
    return fmaxf(e, -60.f);
}

// ------- K0: bf16 casts + layout transforms + cnt zeroing -------------------
__global__ __launch_bounds__(256) void k_cast(
    const float* __restrict__ com, const float* __restrict__ W,
    const float* __restrict__ attn_l, const float* __restrict__ attn_r,
    u16* __restrict__ comb, u16* __restrict__ WbTf, u16* __restrict__ attnT,
    int* __restrict__ cnt, int nFeat, int nNodes)
{
    int i = blockIdx.x * 256 + threadIdx.x;
    if (i < nFeat) { comb[i] = f2bf(com[i]); return; }
    i -= nFeat;
    if (i < NE*DIM*DIM) {
        int t = i / (DIM*DIM), r = i % (DIM*DIM);
        int j = r & 7, f = r >> 3;
        int l15 = f & 15, quad = (f >> 4) & 3, ct = (f >> 6) & 7, s = (f >> 9) & 3;
        int c = ct*16 + l15, k = s*32 + quad*8 + j;
        WbTf[i] = f2bf(W[(size_t)t*DIM*DIM + (size_t)k*DIM + c]);
        return;
    }
    i -= NE*DIM*DIM;
    if (i < NE*16*DIM) {
        int t = i / (16*DIM), r = i % (16*DIM);
        int n = r / DIM, k = r % DIM;
        float v = 0.f;
        if (n < NH)        v = attn_l[((size_t)t*NH + n)*DIM + k];
        else if (n < 2*NH) v = attn_r[((size_t)t*NH + (n-NH))*DIM + k];
        attnT[i] = f2bf(v);
        return;
    }
    i -= NE*16*DIM;
    if (i < nNodes) cnt[i] = 0;   // fused memset (drops a dispatch)
}

// ------- K0b: bucket fill, SPLIT OUT of k_node (r16 attribution round) ------
// r15 evidence: k_node stuck at ~78us across occupancy 3->4 blocks/CU and the
// LDS restage; no modeled resource (MFMA 3.6%, VALU 13%, HBM 17%, L2 ~9%)
// explains it. The un-bounded suspect is this fused tail: 800k device-scope
// atomicAdd-with-return (20-way avg same-address contention) + scattered 4B
// stores, convoyed behind k_node's barrier phases at 16 waves/CU. Standalone
// it runs at full occupancy with pure TLP. Prediction: if atomics were the
// hidden stall, k_node drops to ~30-45us and this runs ~10-25us; if not,
// k_node stays ~70us and this is ~8-15us.
__global__ __launch_bounds__(256) void k_fill(
    const int* __restrict__ src, const int* __restrict__ dst,
    const int* __restrict__ ety, int* __restrict__ cnt,
    int* __restrict__ bucket, int nEdges)
{
    int m = blockIdx.x * 256 + threadIdx.x;
    if (m >= nEdges) return;
    int d = dst[m];
    int j = atomicAdd(&cnt[d], 1);
    if (j < CAP) bucket[(size_t)d*CAP + j] = src[m]*NE + ety[m];
}

// ---------------- K1: MFMA projection + mess + el/er ------------------------
// r14 post-mortem: traffic fixed (FETCH 22 MB) but dur unchanged at 27%
// occupancy (49 KB LDS -> 3 blocks/CU). r15: sB staged in TWO 16 KB halves
// (K s={0,1} then {2,3}; both halves' global loads issued up front into regs,
// so the mid-barrier has no vmcnt stall): LDS 33.8 KB -> 4 blocks/CU ->
// 16 waves/CU. XCD swizzle kept (b -> q,x,t with g=q*8+x).
// r16: bucket-fill tail moved to k_fill (see above) for attribution.
__global__ __launch_bounds__(256) void k_node(
    const float* __restrict__ feat, const u16* __restrict__ comb,
    const float* __restrict__ coll, const u16* __restrict__ WbTf,
    const u16* __restrict__ attnT,
    u16* __restrict__ mess, float* __restrict__ el, float* __restrict__ er,
    int nNodes, int nGroups)
{
    __shared__ __attribute__((aligned(16))) u16 sB[8192];        // 16 KB half of W[t]
    __shared__ __attribute__((aligned(16))) u16 smess[4][16][136];
    const int tid  = threadIdx.x;
    const int b = blockIdx.x;
    const int q = b / (8*NE), r8 = b % (8*NE);
    const int t = r8 >> 3, x = r8 & 7;
    const int g = q*8 + x;
    if (g >= nGroups) return;             // block-uniform (barrier-safe)

    const int wave = tid >> 6, lane = tid & 63;
    const int quad = lane >> 4, l15 = lane & 15;
    const int n0 = (g*4 + wave) * 16;

    // issue ALL W loads up front (regs), stage half 1 to LDS
    const bf8v* wsrc = (const bf8v*)(WbTf + (size_t)t*16384);
    bf8v wregA[4], wregB[4];
    #pragma unroll
    for (int it = 0; it < 4; ++it) wregA[it] = wsrc[it*256 + tid];
    #pragma unroll
    for (int it = 0; it < 4; ++it) wregB[it] = wsrc[1024 + it*256 + tid];
    #pragma unroll
    for (int it = 0; it < 4; ++it)
        *((bf8v*)&sB[(size_t)(it*256 + tid)*8]) = wregA[it];

    // A-fragments straight from f32 feat (in-register RNE cast):
    int rowA = n0 + l15; if (rowA >= nNodes) rowA = nNodes - 1;
    const float* fr = feat + (size_t)rowA*DIM;
    bf8v afrag[4];
    #pragma unroll
    for (int s = 0; s < 4; ++s) {
        float4 xv = *(const float4*)(fr + s*32 + quad*8);
        float4 yv = *(const float4*)(fr + s*32 + quad*8 + 4);
        afrag[s][0] = (short)f2bf(xv.x); afrag[s][1] = (short)f2bf(xv.y);
        afrag[s][2] = (short)f2bf(xv.z); afrag[s][3] = (short)f2bf(xv.w);
        afrag[s][4] = (short)f2bf(yv.x); afrag[s][5] = (short)f2bf(yv.y);
        afrag[s][6] = (short)f2bf(yv.z); afrag[s][7] = (short)f2bf(yv.w);
    }

    float mk_r[4];
    #pragma unroll
    for (int rr = 0; rr < 4; ++rr) {
        int n = n0 + quad*4 + rr; if (n >= nNodes) n = nNodes - 1;
        mk_r[rr] = coll[(size_t)n*NE + t];
    }

    f4v acc[8];
    #pragma unroll
    for (int ct = 0; ct < 8; ++ct) acc[ct] = (f4v){0.f, 0.f, 0.f, 0.f};
    __syncthreads();
    #pragma unroll
    for (int s = 0; s < 2; ++s) {          // K half 1
        #pragma unroll
        for (int ct = 0; ct < 8; ++ct) {
            bf8v bfrag = *(const bf8v*)&sB[(size_t)((s*8 + ct)*64 + lane)*8];
            acc[ct] = __builtin_amdgcn_mfma_f32_16x16x32_bf16(afrag[s], bfrag, acc[ct], 0, 0, 0);
        }
    }
    __syncthreads();                       // all waves done with half 1
    #pragma unroll
    for (int it = 0; it < 4; ++it)
        *((bf8v*)&sB[(size_t)(it*256 + tid)*8]) = wregB[it];
    __syncthreads();
    #pragma unroll
    for (int s = 2; s < 4; ++s) {          // K half 2
        #pragma unroll
        for (int ct = 0; ct < 8; ++ct) {
            bf8v bfrag = *(const bf8v*)&sB[(size_t)(((s-2)*8 + ct)*64 + lane)*8];
            acc[ct] = __builtin_amdgcn_mfma_f32_16x16x32_bf16(afrag[s], bfrag, acc[ct], 0, 0, 0);
        }
    }
    #pragma unroll
    for (int rr = 0; rr < 4; ++rr) {
        #pragma unroll
        for (int ct = 0; ct < 8; ++ct) {
            float mval = (mk_r[rr] != 0.f ? acc[ct][rr] : 0.f);
            smess[wave][quad*4 + rr][ct*16 + l15] = f2bf(mval);
        }
    }
    asm volatile("" ::: "memory");   // pin cross-lane LDS write->read order
    #pragma unroll
    for (int it = 0; it < 4; ++it) {
        int row = it*4 + quad;
        int n = n0 + row; if (n >= nNodes) n = nNodes - 1;
        bf8v v  = *(const bf8v*)&smess[wave][row][l15*8];
        bf8v cb = *(const bf8v*)(comb + (size_t)n*DIM + l15*8);
        bf8v res;
        #pragma unroll
        for (int e = 0; e < 8; ++e)
            res[e] = (short)f2bf(bf2f((u16)v[e]) + bf2f((u16)cb[e]));
        if (n0 + row < nNodes)
            *(bf8v*)(mess + ((size_t)n*NE + t)*DIM + l15*8) = res;
        *(bf8v*)&smess[wave][row][l15*8] = res;
    }
    asm volatile("" ::: "memory");
    const u16* at = attnT + (size_t)t*16*DIM;
    f4v eacc = (f4v){0.f, 0.f, 0.f, 0.f};
    #pragma unroll
    for (int s = 0; s < 4; ++s) {
        bf8v am = *(const bf8v*)&smess[wave][l15][s*32 + quad*8];
        bf8v bt = *(const bf8v*)(at + (size_t)l15*DIM + s*32 + quad*8);
        eacc = __builtin_amdgcn_mfma_f32_16x16x32_bf16(am, bt, eacc, 0, 0, 0);
    }
    if (l15 < 8) {
        float* dstp = (l15 < 4) ? el : er;
        int h = l15 & 3;
        #pragma unroll
        for (int rr = 0; rr < 4; ++rr) {
            int n = n0 + quad*4 + rr;
            if (n < nNodes) dstp[(size_t)n*NHT + h*NE + t] = eacc[rr];
        }
    }
}

// ------- K2: mega-fused den + coeff + rst + ELU (wave per dst, buckets) -----
#define EB 16
__global__ __launch_bounds__(256) void k_rst2(
    const int* __restrict__ cnt, const int* __restrict__ bucket,
    const float* __restrict__ el, const float* __restrict__ er,
    const u16* __restrict__ mess, float* __restrict__ out, int nNodes)
{
    __shared__ float sden[4][NHT];   // wave-private den_r
    __shared__ float ser[4][NHT];    // wave-private er row
    __shared__ float scf[4][EB];     // wave-private parked coeffs
    __shared__ int   spk[4][EB];     // wave-private parked epacks
    const int tid  = threadIdx.x;
    const int wave = tid >> 6, lane = tid & 63;
    const int d = blockIdx.x*4 + wave;
    if (d >= nNodes) return;         // wave-uniform
    int deg = cnt[d]; if (deg > CAP) deg = CAP;
    const int* eb = bucket + (size_t)d*CAP;

    // ---- den phase: 60 lanes = 3 edge-slots x 20 channels, unroll x2 ----
    const int e3 = lane / NHT, k20 = lane % NHT;
    float er_k = er[(size_t)d*NHT + k20];
    float accd = 0.f;
    for (int j = 0; j < deg; j += 6) {
        int p1 = -1, p2 = -1;
        if (e3 < 3) {
            int j1 = j + e3, j2 = j + 3 + e3;
            if (j1 < deg) p1 = eb[j1];
            if (j2 < deg) p2 = eb[j2];
        }
        float x1 = 0.f, x2 = 0.f;
        if (p1 >= 0) x1 = el[(size_t)(p1/NE)*NHT + k20] + er_k;
        if (p2 >= 0) x2 = el[(size_t)(p2/NE)*NHT + k20] + er_k;
        if (p1 >= 0) accd += __expf(edge_act(x1));
        if (p2 >= 0) accd += __expf(edge_act(x2));
    }
    float v1 = __shfl(accd, lane + 20, 64);
    float v2 = __shfl(accd, lane + 40, 64);
    if (lane < NHT) {
        sden[wave][lane] = 1.f / (accd + v1 + v2);
        ser[wave][lane]  = er_k;
    }
    asm volatile("" ::: "memory");

    // ---- rst phase: batches of EB edges, two roles per batch ----
    const int eA = lane >> 2, hA = lane & 3;
    float a0 = 0.f, a1 = 0.f;
    for (int j0 = 0; j0 < deg; j0 += EB) {
        int nb = deg - j0; if (nb > EB) nb = EB;
        float c = 0.f;
        int p = 0;
        if (eA < nb) {
            p = eb[j0 + eA];
            int k = hA*NE + (p % NE);
            c = __expf(edge_act(el[(size_t)(p/NE)*NHT + k] + ser[wave][k])) * sden[wave][k];
        }
        c += __shfl_xor(c, 1, 64);
        c += __shfl_xor(c, 2, 64);
        if (eA < nb && hA == 0) { scf[wave][eA] = c; spk[wave][eA] = p; }
        asm volatile("" ::: "memory");
        if (nb == EB) {
            #pragma unroll
            for (int e2 = 0; e2 < EB; ++e2) {
                int p2 = spk[wave][e2];
                float cf = scf[wave][e2];
                u32 qq = *(const u32*)(mess + (size_t)p2*DIM + lane*2);
                a0 += bf2f((u16)(qq & 0xFFFF)) * cf;
                a1 += bf2f((u16)(qq >> 16))    * cf;
            }
        } else {
            for (int e2 = 0; e2 < nb; ++e2) {
                int p2 = spk[wave][e2];
                float cf = scf[wave][e2];
                u32 qq = *(const u32*)(mess + (size_t)p2*DIM + lane*2);
                a0 += bf2f((u16)(qq & 0xFFFF)) * cf;
                a1 += bf2f((u16)(qq >> 16))    * cf;
            }
        }
        asm volatile("" ::: "memory");
    }
    float2 r;
    r.x = a0 > 0.f ? a0 : expm1f(a0);
    r.y = a1 > 0.f ? a1 : expm1f(a1);
    *(float2*)(out + (size_t)d*DIM + lane*2) = r;
}

extern "C" void kernel_launch(void* const* d_in, const int* in_sizes, int n_in,
                              void* d_out, int out_size, void* d_ws, size_t ws_size,
                              hipStream_t stream)
{
    const float* feat   = (const float*)d_in[0];
    const float* com    = (const float*)d_in[1];
    const float* coll   = (const float*)d_in[2];
    const float* W      = (const float*)d_in[3];
    const float* attn_l = (const float*)d_in[4];
    const float* attn_r = (const float*)d_in[5];
    const int*   src    = (const int*)d_in[6];
    const int*   dst    = (const int*)d_in[7];
    const int*   ety    = (const int*)d_in[8];
    float* out = (float*)d_out;

    const int N = in_sizes[0] / DIM;   // 40000
    const int M = in_sizes[6];         // 800000

    // d_out overlay: comb bf16 (10.24 MB) -- dead before k_rst2 writes out.
    u16* comb = (u16*)d_out;

    // workspace (~68.2 MB): mess | el | er | WbTf | attnT | bucket | cnt
    auto al16 = [](size_t x) { return (x + 15) & ~(size_t)15; };
    char* w = (char*)d_ws;
    size_t off = 0;
    u16*  mess   = (u16*)(w + off);  off += al16((size_t)N*NE*DIM*sizeof(u16));
    float* el    = (float*)(w + off); off += al16((size_t)N*NHT*sizeof(float));
    float* er    = (float*)(w + off); off += al16((size_t)N*NHT*sizeof(float));
    u16*  WbTf   = (u16*)(w + off);  off += al16((size_t)NE*DIM*DIM*sizeof(u16));
    u16*  attnT  = (u16*)(w + off);  off += al16((size_t)NE*16*DIM*sizeof(u16));
    int*  bucket = (int*)(w + off);  off += al16((size_t)N*CAP*sizeof(int));
    int*  cnt    = (int*)(w + off);  off += al16((size_t)N*sizeof(int));

    int castTotal = N*DIM + NE*DIM*DIM + NE*16*DIM + N;   // comb+W+attn+cnt0
    k_cast<<<(castTotal + 255)/256, 256, 0, stream>>>(
        com, W, attn_l, attn_r, comb, WbTf, attnT, cnt, N*DIM, N);
    k_fill<<<(M + 255)/256, 256, 0, stream>>>(src, dst, ety, cnt, bucket, M);
    int nGroups = (N + 63) / 64;          // 625
    int qBlocks = (nGroups + 7) / 8;      // 79 -> grid covers g=q*8+x fully
    k_node<<<qBlocks * 8 * NE, 256, 0, stream>>>(
        feat, comb, coll, WbTf, attnT, mess, el, er, N, nGroups);
    k_rst2<<<(N + 3)/4, 256, 0, stream>>>(cnt, bucket, el, er, mess, out, N);
}

// Round 2
// 227.101 us; speedup vs baseline: 1.0616x; 1.0616x over previous
//
#include <hip/hip_runtime.h>
#include <hip/hip_bf16.h>

// Problem constants (fixed by the reference)
#define DIM 128      // IN_DIM == COM_DIM
#define NE  5        // N_ETYPE
#define NH  4        // N_HEADS
#define NHT (NH*NE)  // 20 channels, layout k = h*NE + t
#define CAP 64       // bucket capacity per dst (Poisson(20) max ~50; P(>=64)~2e-9)

typedef unsigned short u16;
typedef unsigned int   u32;
typedef __attribute__((ext_vector_type(8))) short bf8v;  // 8 bf16 = 4 VGPRs (MFMA A/B frag)
typedef __attribute__((ext_vector_type(4))) float f4v;   // MFMA C/D frag

__device__ __forceinline__ float bf2f(u16 u) {
    union { u32 i; float f; } v; v.i = ((u32)u) << 16; return v.f;
}
__device__ __forceinline__ u16 f2bf(float f) {
    union { float f; u32 i; } v; v.f = f;
    u32 x = v.i;
    return (u16)((x + 0x7FFFu + ((x >> 16) & 1u)) >> 16);  // RNE
}
// leaky-relu + clamp to +-60 (overflow armor; softmax ratio needs no max-sub)
__device__ __forceinline__ float edge_act(float e) {
    e = e >= 0.f ? e : 0.2f * e;
    e = fminf(e, 60.f);
    return fmaxf(e, -60.f);
}

// ------- K0: bf16 casts + layout transforms + cnt zeroing -------------------
// r17: also pre-casts feat -> bf16 (featb). k_node was re-reading feat f32
// 5x (once per etype) = 102 MB of L3 traffic + ~100 VALU/thread of f2bf;
// bf16 halves the re-read stream and makes A-frags direct 16B loads.
__global__ __launch_bounds__(256) void k_cast(
    const float* __restrict__ com, const float* __restrict__ feat,
    const float* __restrict__ W,
    const float* __restrict__ attn_l, const float* __restrict__ attn_r,
    u16* __restrict__ comb, u16* __restrict__ featb,
    u16* __restrict__ WbTf, u16* __restrict__ attnT,
    int* __restrict__ cnt, int nFeat, int nNodes)
{
    int i = blockIdx.x * 256 + threadIdx.x;
    if (i < nFeat) { comb[i] = f2bf(com[i]); return; }
    i -= nFeat;
    if (i < nFeat) { featb[i] = f2bf(feat[i]); return; }
    i -= nFeat;
    if (i < NE*DIM*DIM) {
        int t = i / (DIM*DIM), r = i % (DIM*DIM);
        int j = r & 7, f = r >> 3;
        int l15 = f & 15, quad = (f >> 4) & 3, ct = (f >> 6) & 7, s = (f >> 9) & 3;
        int c = ct*16 + l15, k = s*32 + quad*8 + j;
        WbTf[i] = f2bf(W[(size_t)t*DIM*DIM + (size_t)k*DIM + c]);
        return;
    }
    i -= NE*DIM*DIM;
    if (i < NE*16*DIM) {
        int t = i / (16*DIM), r = i % (16*DIM);
        int n = r / DIM, k = r % DIM;
        float v = 0.f;
        if (n < NH)        v = attn_l[((size_t)t*NH + n)*DIM + k];
        else if (n < 2*NH) v = attn_r[((size_t)t*NH + (n-NH))*DIM + k];
        attnT[i] = f2bf(v);
        return;
    }
    i -= NE*16*DIM;
    if (i < nNodes) cnt[i] = 0;   // fused memset (drops a dispatch)
}

// ---------------- K1: MFMA projection + mess + el/er  ∥  bucket fill --------
// r16 post-mortem: splitting the fill out dropped k_node below 62us but cost
// +18us total (k_fill ~30us fully serial on the stream). r17: fill and node
// have ZERO data dependence -> merge as disjoint BLOCK RANGES in one grid,
// 1:1 interleaved (even=node, odd=fill until fill exhausted) so atomic-bound
// fill waves co-reside with MFMA/L3-bound node waves on every CU throughout.
// A-frags now load bf16 featb directly (r17, see k_cast note).
__global__ __launch_bounds__(256) void k_node(
    const u16* __restrict__ featb, const u16* __restrict__ comb,
    const float* __restrict__ coll, const u16* __restrict__ WbTf,
    const u16* __restrict__ attnT,
    u16* __restrict__ mess, float* __restrict__ el, float* __restrict__ er,
    const int* __restrict__ src, const int* __restrict__ dst,
    const int* __restrict__ ety, int* __restrict__ cnt,
    int* __restrict__ bucket,
    int nNodes, int nGroups, int nEdges, int nFillBlocks)
{
    __shared__ __attribute__((aligned(16))) u16 sB[8192];        // 16 KB half of W[t]
    __shared__ __attribute__((aligned(16))) u16 smess[4][16][136];
    const int tid  = threadIdx.x;

    // ---- block-range split: interleave node/fill for co-residency ----
    const int bb = blockIdx.x;
    int widx; bool isFill;
    if (bb < 2*nFillBlocks) { isFill = (bb & 1); widx = bb >> 1; }
    else                    { isFill = false;    widx = bb - nFillBlocks; }
    if (isFill) {
        int m = widx*256 + tid;
        if (m < nEdges) {
            int d = dst[m];
            int j = atomicAdd(&cnt[d], 1);
            if (j < CAP) bucket[(size_t)d*CAP + j] = src[m]*NE + ety[m];
        }
        return;   // block-uniform exit, no barrier in this path
    }

    const int b = widx;
    const int q = b / (8*NE), r8 = b % (8*NE);
    const int t = r8 >> 3, x = r8 & 7;
    const int g = q*8 + x;
    if (g >= nGroups) return;             // block-uniform (barrier-safe)

    const int wave = tid >> 6, lane = tid & 63;
    const int quad = lane >> 4, l15 = lane & 15;
    const int n0 = (g*4 + wave) * 16;

    // issue ALL W loads up front (regs), stage half 1 to LDS
    const bf8v* wsrc = (const bf8v*)(WbTf + (size_t)t*16384);
    bf8v wregA[4], wregB[4];
    #pragma unroll
    for (int it = 0; it < 4; ++it) wregA[it] = wsrc[it*256 + tid];
    #pragma unroll
    for (int it = 0; it < 4; ++it) wregB[it] = wsrc[1024 + it*256 + tid];
    #pragma unroll
    for (int it = 0; it < 4; ++it)
        *((bf8v*)&sB[(size_t)(it*256 + tid)*8]) = wregA[it];

    // A-fragments: direct bf16 16B loads (r17)
    int rowA = n0 + l15; if (rowA >= nNodes) rowA = nNodes - 1;
    const u16* fr = featb + (size_t)rowA*DIM;
    bf8v afrag[4];
    #pragma unroll
    for (int s = 0; s < 4; ++s)
        afrag[s] = *(const bf8v*)(fr + s*32 + quad*8);

    float mk_r[4];
    #pragma unroll
    for (int rr = 0; rr < 4; ++rr) {
        int n = n0 + quad*4 + rr; if (n >= nNodes) n = nNodes - 1;
        mk_r[rr] = coll[(size_t)n*NE + t];
    }

    f4v acc[8];
    #pragma unroll
    for (int ct = 0; ct < 8; ++ct) acc[ct] = (f4v){0.f, 0.f, 0.f, 0.f};
    __syncthreads();
    #pragma unroll
    for (int s = 0; s < 2; ++s) {          // K half 1
        #pragma unroll
        for (int ct = 0; ct < 8; ++ct) {
            bf8v bfrag = *(const bf8v*)&sB[(size_t)((s*8 + ct)*64 + lane)*8];
            acc[ct] = __builtin_amdgcn_mfma_f32_16x16x32_bf16(afrag[s], bfrag, acc[ct], 0, 0, 0);
        }
    }
    __syncthreads();                       // all waves done with half 1
    #pragma unroll
    for (int it = 0; it < 4; ++it)
        *((bf8v*)&sB[(size_t)(it*256 + tid)*8]) = wregB[it];
    __syncthreads();
    #pragma unroll
    for (int s = 2; s < 4; ++s) {          // K half 2
        #pragma unroll
        for (int ct = 0; ct < 8; ++ct) {
            bf8v bfrag = *(const bf8v*)&sB[(size_t)(((s-2)*8 + ct)*64 + lane)*8];
            acc[ct] = __builtin_amdgcn_mfma_f32_16x16x32_bf16(afrag[s], bfrag, acc[ct], 0, 0, 0);
        }
    }
    #pragma unroll
    for (int rr = 0; rr < 4; ++rr) {
        #pragma unroll
        for (int ct = 0; ct < 8; ++ct) {
            float mval = (mk_r[rr] != 0.f ? acc[ct][rr] : 0.f);
            smess[wave][quad*4 + rr][ct*16 + l15] = f2bf(mval);
        }
    }
    asm volatile("" ::: "memory");   // pin cross-lane LDS write->read order
    #pragma unroll
    for (int it = 0; it < 4; ++it) {
        int row = it*4 + quad;
        int n = n0 + row; if (n >= nNodes) n = nNodes - 1;
        bf8v v  = *(const bf8v*)&smess[wave][row][l15*8];
        bf8v cb = *(const bf8v*)(comb + (size_t)n*DIM + l15*8);
        bf8v res;
        #pragma unroll
        for (int e = 0; e < 8; ++e)
            res[e] = (short)f2bf(bf2f((u16)v[e]) + bf2f((u16)cb[e]));
        if (n0 + row < nNodes)
            *(bf8v*)(mess + ((size_t)n*NE + t)*DIM + l15*8) = res;
        *(bf8v*)&smess[wave][row][l15*8] = res;
    }
    asm volatile("" ::: "memory");
    const u16* at = attnT + (size_t)t*16*DIM;
    f4v eacc = (f4v){0.f, 0.f, 0.f, 0.f};
    #pragma unroll
    for (int s = 0; s < 4; ++s) {
        bf8v am = *(const bf8v*)&smess[wave][l15][s*32 + quad*8];
        bf8v bt = *(const bf8v*)(at + (size_t)l15*DIM + s*32 + quad*8);
        eacc = __builtin_amdgcn_mfma_f32_16x16x32_bf16(am, bt, eacc, 0, 0, 0);
    }
    if (l15 < 8) {
        float* dstp = (l15 < 4) ? el : er;
        int h = l15 & 3;
        #pragma unroll
        for (int rr = 0; rr < 4; ++rr) {
            int n = n0 + quad*4 + rr;
            if (n < nNodes) dstp[(size_t)n*NHT + h*NE + t] = eacc[rr];
        }
    }
}

// ------- K2: mega-fused den + coeff + rst + ELU (wave per dst, buckets) -----
#define EB 16
__global__ __launch_bounds__(256) void k_rst2(
    const int* __restrict__ cnt, const int* __restrict__ bucket,
    const float* __restrict__ el, const float* __restrict__ er,
    const u16* __restrict__ mess, float* __restrict__ out, int nNodes)
{
    __shared__ float sden[4][NHT];   // wave-private den_r
    __shared__ float ser[4][NHT];    // wave-private er row
    __shared__ float scf[4][EB];     // wave-private parked coeffs
    __shared__ int   spk[4][EB];     // wave-private parked epacks
    const int tid  = threadIdx.x;
    const int wave = tid >> 6, lane = tid & 63;
    const int d = blockIdx.x*4 + wave;
    if (d >= nNodes) return;         // wave-uniform
    int deg = cnt[d]; if (deg > CAP) deg = CAP;
    const int* eb = bucket + (size_t)d*CAP;

    // ---- den phase: 60 lanes = 3 edge-slots x 20 channels, unroll x2 ----
    const int e3 = lane / NHT, k20 = lane % NHT;
    float er_k = er[(size_t)d*NHT + k20];
    float accd = 0.f;
    for (int j = 0; j < deg; j += 6) {
        int p1 = -1, p2 = -1;
        if (e3 < 3) {
            int j1 = j + e3, j2 = j + 3 + e3;
            if (j1 < deg) p1 = eb[j1];
            if (j2 < deg) p2 = eb[j2];
        }
        float x1 = 0.f, x2 = 0.f;
        if (p1 >= 0) x1 = el[(size_t)(p1/NE)*NHT + k20] + er_k;
        if (p2 >= 0) x2 = el[(size_t)(p2/NE)*NHT + k20] + er_k;
        if (p1 >= 0) accd += __expf(edge_act(x1));
        if (p2 >= 0) accd += __expf(edge_act(x2));
    }
    float v1 = __shfl(accd, lane + 20, 64);
    float v2 = __shfl(accd, lane + 40, 64);
    if (lane < NHT) {
        sden[wave][lane] = 1.f / (accd + v1 + v2);
        ser[wave][lane]  = er_k;
    }
    asm volatile("" ::: "memory");

    // ---- rst phase: batches of EB edges, two roles per batch ----
    const int eA = lane >> 2, hA = lane & 3;
    float a0 = 0.f, a1 = 0.f;
    for (int j0 = 0; j0 < deg; j0 += EB) {
        int nb = deg - j0; if (nb > EB) nb = EB;
        float c = 0.f;
        int p = 0;
        if (eA < nb) {
            p = eb[j0 + eA];
            int k = hA*NE + (p % NE);
            c = __expf(edge_act(el[(size_t)(p/NE)*NHT + k] + ser[wave][k])) * sden[wave][k];
        }
        c += __shfl_xor(c, 1, 64);
        c += __shfl_xor(c, 2, 64);
        if (eA < nb && hA == 0) { scf[wave][eA] = c; spk[wave][eA] = p; }
        asm volatile("" ::: "memory");
        if (nb == EB) {
            #pragma unroll
            for (int e2 = 0; e2 < EB; ++e2) {
                int p2 = spk[wave][e2];
                float cf = scf[wave][e2];
                u32 qq = *(const u32*)(mess + (size_t)p2*DIM + lane*2);
                a0 += bf2f((u16)(qq & 0xFFFF)) * cf;
                a1 += bf2f((u16)(qq >> 16))    * cf;
            }
        } else {
            for (int e2 = 0; e2 < nb; ++e2) {
                int p2 = spk[wave][e2];
                float cf = scf[wave][e2];
                u32 qq = *(const u32*)(mess + (size_t)p2*DIM + lane*2);
                a0 += bf2f((u16)(qq & 0xFFFF)) * cf;
                a1 += bf2f((u16)(qq >> 16))    * cf;
            }
        }
        asm volatile("" ::: "memory");
    }
    float2 r;
    r.x = a0 > 0.f ? a0 : expm1f(a0);
    r.y = a1 > 0.f ? a1 : expm1f(a1);
    *(float2*)(out + (size_t)d*DIM + lane*2) = r;
}

extern "C" void kernel_launch(void* const* d_in, const int* in_sizes, int n_in,
                              void* d_out, int out_size, void* d_ws, size_t ws_size,
                              hipStream_t stream)
{
    const float* feat   = (const float*)d_in[0];
    const float* com    = (const float*)d_in[1];
    const float* coll   = (const float*)d_in[2];
    const float* W      = (const float*)d_in[3];
    const float* attn_l = (const float*)d_in[4];
    const float* attn_r = (const float*)d_in[5];
    const int*   src    = (const int*)d_in[6];
    const int*   dst    = (const int*)d_in[7];
    const int*   ety    = (const int*)d_in[8];
    float* out = (float*)d_out;

    const int N = in_sizes[0] / DIM;   // 40000
    const int M = in_sizes[6];         // 800000

    // d_out overlay: comb bf16 (10.24 MB) + featb bf16 (10.24 MB) = exactly
    // out_size; both dead before k_rst2 writes out.
    u16* comb  = (u16*)d_out;
    u16* featb = (u16*)d_out + (size_t)N*DIM;

    // workspace (~68.2 MB): mess | el | er | WbTf | attnT | bucket | cnt
    auto al16 = [](size_t x) { return (x + 15) & ~(size_t)15; };
    char* w = (char*)d_ws;
    size_t off = 0;
    u16*  mess   = (u16*)(w + off);  off += al16((size_t)N*NE*DIM*sizeof(u16));
    float* el    = (float*)(w + off); off += al16((size_t)N*NHT*sizeof(float));
    float* er    = (float*)(w + off); off += al16((size_t)N*NHT*sizeof(float));
    u16*  WbTf   = (u16*)(w + off);  off += al16((size_t)NE*DIM*DIM*sizeof(u16));
    u16*  attnT  = (u16*)(w + off);  off += al16((size_t)NE*16*DIM*sizeof(u16));
    int*  bucket = (int*)(w + off);  off += al16((size_t)N*CAP*sizeof(int));
    int*  cnt    = (int*)(w + off);  off += al16((size_t)N*sizeof(int));

    int castTotal = 2*N*DIM + NE*DIM*DIM + NE*16*DIM + N;   // comb+featb+W+attn+cnt0
    k_cast<<<(castTotal + 255)/256, 256, 0, stream>>>(
        com, feat, W, attn_l, attn_r, comb, featb, WbTf, attnT, cnt, N*DIM, N);
    int nGroups = (N + 63) / 64;          // 625
    int qBlocks = (nGroups + 7) / 8;      // 79 -> grid covers g=q*8+x fully
    int nodeBlocks = qBlocks * 8 * NE;    // 3160
    int fillBlocks = (M + 255) / 256;     // 3125 (must be <= nodeBlocks)
    k_node<<<nodeBlocks + fillBlocks, 256, 0, stream>>>(
        featb, comb, coll, WbTf, attnT, mess, el, er,
        src, dst, ety, cnt, bucket, N, nGroups, M, fillBlocks);
    k_rst2<<<(N + 3)/4, 256, 0, stream>>>(cnt, bucket, el, er, mess, out, N);
}